// Round 14
// baseline (222.000 us; speedup 1.0000x reference)
//
#include <hip/hip_runtime.h>
#include <hip/hip_cooperative_groups.h>

// VolumeRenderer R14. R13 neutral -> render (~35us) is at its TD divergent-
// gather + VALU wall; cvt ~12us near streaming floor; remaining controllable
// cost is DISPATCH COUNT (~8-10us each in graph replay; the 45us/iter ws
// re-poison fill is harness-fixed). R14 merges cvt+render into ONE
// cooperative kernel: phase 1 converts fp32 grid -> brick-ordered u8x4
// (coalesced, ~7us), grid.sync(), phase 2 renders (NSEG=4 structure of R12).
// Host checks hipLaunchCooperativeKernel's rc and falls back to the proven
// 2-kernel path. Math identical to R11b/R12/R13 (absmax 0.00390625).

namespace cg = cooperative_groups;

constexpr int   R_DIM    = 128;
constexpr int   N_VOX    = R_DIM * R_DIM * R_DIM;
constexpr int   N_STEPS  = 192;
constexpr int   NSEG     = 4;
constexpr int   SEG_LEN  = N_STEPS / NSEG;   // 48
constexpr float STEP_SZ  = 0.001f;
constexpr float CUBE_SZ  = 1.0f / 128.0f;
constexpr int   PIPE     = 8;                // back to R12's granularity
constexpr float SIG_MAX  = 5.5f;

__device__ __forceinline__ float sigmoid_fast(float x) {
    return __builtin_amdgcn_rcpf(1.0f + __expf(-x));
}

__device__ __forceinline__ int clamp_idx(float v) {
    int i = (int)floorf(v);
    i = i < 0 ? 0 : i;
    i = i > (R_DIM - 1) ? (R_DIM - 1) : i;
    return i;
}

// One geometric DDA step -> cell coords + exact delta. Single definition, all
// IEEE __f*_rn (no contraction): prewalk/render t-sequences bit-identical.
// smin==0 exactly (f in [0,1] -> every per-axis lo <= 0).
__device__ __forceinline__ void geom_step(
    float tl, float tmax,
    float ox, float oy, float oz, float dx, float dy, float dz,
    float ix, float iy, float iz,
    int& i0, int& i1, int& i2, float& d)
{
    float px = __fmul_rn(__fadd_rn(ox, __fmul_rn(tl, dx)), (float)R_DIM);
    float py = __fmul_rn(__fadd_rn(oy, __fmul_rn(tl, dy)), (float)R_DIM);
    float pz = __fmul_rn(__fadd_rn(oz, __fmul_rn(tl, dz)), (float)R_DIM);
    i0 = clamp_idx(px);
    i1 = clamp_idx(py);
    i2 = clamp_idx(pz);

    float fx = __fsub_rn(px, (float)i0);
    float fy = __fsub_rn(py, (float)i1);
    float fz = __fsub_rn(pz, (float)i2);

    float t1x = __fmul_rn(-fx, ix), t2x = __fadd_rn(t1x, ix);
    float t1y = __fmul_rn(-fy, iy), t2y = __fadd_rn(t1y, iy);
    float t1z = __fmul_rn(-fz, iz), t2z = __fadd_rn(t1z, iz);
    float hix = fmaxf(t1x, t2x);
    float hiy = fmaxf(t1y, t2y);
    float hiz = fmaxf(t1z, t2z);
    float smax = fminf(fminf(fminf(hix, hiy), hiz), 1e9f);

    d = __fadd_rn(__fmul_rn(smax, CUBE_SZ), STEP_SZ);
    d = (tl < tmax) ? d : 0.0f;   // inactive -> exact no-op (t frozen)
}

__device__ __forceinline__ void ray_setup(
    const float* __restrict__ origins, const float* __restrict__ dirs, int i,
    float& ox, float& oy, float& oz, float& dx, float& dy, float& dz,
    float& ix, float& iy, float& iz, float& tmin, float& tmax)
{
    ox = origins[3 * i + 0];
    oy = origins[3 * i + 1];
    oz = origins[3 * i + 2];
    dx = dirs[3 * i + 0];
    dy = dirs[3 * i + 1];
    dz = dirs[3 * i + 2];

    float n2 = __fadd_rn(__fadd_rn(__fmul_rn(dx, dx), __fmul_rn(dy, dy)),
                         __fmul_rn(dz, dz));
    float nrm = sqrtf(n2);
    dx = dx / nrm;
    dy = dy / nrm;
    dz = dz / nrm;

    ix = 1.0f / __fadd_rn(dx, 1e-9f);
    iy = 1.0f / __fadd_rn(dy, 1e-9f);
    iz = 1.0f / __fadd_rn(dz, 1e-9f);

    float t1x = __fmul_rn(-ox, ix), t2x = __fadd_rn(t1x, ix);
    float t1y = __fmul_rn(-oy, iy), t2y = __fadd_rn(t1y, iy);
    float t1z = __fmul_rn(-oz, iz), t2z = __fadd_rn(t1z, iz);
    float lox = fminf(t1x, t2x), hix = fmaxf(t1x, t2x);
    float loy = fminf(t1y, t2y), hiy = fmaxf(t1y, t2y);
    float loz = fminf(t1z, t2z), hiz = fmaxf(t1z, t2z);
    tmin = fmaxf(fmaxf(fmaxf(lox, loy), loz), 0.0f);
    tmax = fminf(fminf(fminf(hix, hiy), hiz), 1e9f);
}

__device__ __forceinline__ unsigned pack_voxel(float4 v) {
    unsigned ur = (unsigned)__float2int_rn(sigmoid_fast(v.x) * 255.0f);
    unsigned ug = (unsigned)__float2int_rn(sigmoid_fast(v.y) * 255.0f);
    unsigned ub = (unsigned)__float2int_rn(sigmoid_fast(v.z) * 255.0f);
    unsigned us = (unsigned)__float2int_rn(
        fminf(fmaxf(v.w, 0.0f), SIG_MAX) * (255.0f / SIG_MAX));
    return ur | (ug << 8) | (ub << 16) | (us << 24);
}

// Convert one uint4 (= brick bid, slot j = 4 z-consecutive voxels).
__device__ __forceinline__ void cvt_one(
    const float4* __restrict__ g, uint4* __restrict__ gq4, int u)
{
    int bid = u >> 4;
    int j   = u & 15;
    int bx = bid >> 10, by = (bid >> 5) & 31, bz = bid & 31;
    int lx = j >> 2, ly = j & 3;
    int x = (bx << 2) | lx;
    int y = (by << 2) | ly;
    int src = (x * R_DIM + y) * R_DIM + (bz << 2);
    float4 v0 = g[src + 0];
    float4 v1 = g[src + 1];
    float4 v2 = g[src + 2];
    float4 v3 = g[src + 3];
    uint4 o;
    o.x = pack_voxel(v0);
    o.y = pack_voxel(v1);
    o.z = pack_voxel(v2);
    o.w = pack_voxel(v3);
    gq4[bid * 16 + j] = o;
}

// ---- shared render body (phase 2 / standalone) -----------------------------
__device__ __forceinline__ void render_body(
    const unsigned int* __restrict__ gq,
    const float* __restrict__ origins,
    const float* __restrict__ dirs,
    float* __restrict__ out,
    float4* lds, int blk)
{
    int lane = threadIdx.x & 63;
    int seg  = threadIdx.x >> 6;
    int i = blk * 64 + lane;

    float ox, oy, oz, dx, dy, dz, ix, iy, iz, tmin, tmax;
    ray_setup(origins, dirs, i, ox, oy, oz, dx, dy, dz, ix, iy, iz, tmin, tmax);

    float t = tmin;

    // prewalk: seg*48 geometry-only steps (bit-exact, no loads)
    int pre_chunks = seg * (SEG_LEN / PIPE);
    for (int c = 0; c < pre_chunks; ++c) {
        if (t >= tmax) break;
        #pragma unroll
        for (int p = 0; p < PIPE; ++p) {
            int i0, i1, i2; float d;
            geom_step(t, tmax, ox, oy, oz, dx, dy, dz, ix, iy, iz,
                      i0, i1, i2, d);
            t = __fadd_rn(t, d);
        }
    }

    float light = 1.0f;
    float ar = 0.0f, ag = 0.0f, ab = 0.0f;

    for (int chunk = 0; chunk < SEG_LEN / PIPE; ++chunk) {
        if (t >= tmax) break;

        unsigned int val[PIPE];
        float del[PIPE];
        float tl = t;

        #pragma unroll
        for (int p = 0; p < PIPE; ++p) {
            int i0, i1, i2; float d;
            geom_step(tl, tmax, ox, oy, oz, dx, dy, dz, ix, iy, iz,
                      i0, i1, i2, d);
            unsigned bid = ((unsigned)(i0 >> 2) << 10) |
                           ((unsigned)(i1 >> 2) << 5) |
                           (unsigned)(i2 >> 2);
            unsigned loc = ((unsigned)(i0 & 3) << 4) |
                           ((unsigned)(i1 & 3) << 2) |
                           (unsigned)(i2 & 3);
            val[p] = gq[(bid << 6) | loc];   // dead voxel: sigma-u8==0 -> att=1
            del[p] = d;
            tl = __fadd_rn(tl, d);
        }

        #pragma unroll
        for (int p = 0; p < PIPE; ++p) {
            unsigned int v = val[p];
            float r  = (float)(v & 255u)         * (1.0f / 255.0f);
            float gg = (float)((v >> 8) & 255u)  * (1.0f / 255.0f);
            float b  = (float)((v >> 16) & 255u) * (1.0f / 255.0f);
            float sg = (float)(v >> 24)          * (SIG_MAX / 255.0f);
            float att = __expf(-del[p] * sg);
            float w = light * (1.0f - att);
            ar = fmaf(w, r, ar);
            ag = fmaf(w, gg, ag);
            ab = fmaf(w, b, ab);
            light *= att;
        }

        t = tl;
    }

    if (seg > 0) {
        lds[(seg - 1) * 64 + lane] = make_float4(ar, ag, ab, light);
    }
    __syncthreads();
    if (seg == 0) {
        float4 s1 = lds[0 * 64 + lane];
        float4 s2 = lds[1 * 64 + lane];
        float4 s3 = lds[2 * 64 + lane];
        float r3 = s3.x + s3.w, g3 = s3.y + s3.w, b3 = s3.z + s3.w;
        float r2 = fmaf(s2.w, r3, s2.x);
        float g2 = fmaf(s2.w, g3, s2.y);
        float b2 = fmaf(s2.w, b3, s2.z);
        float r1 = fmaf(s1.w, r2, s1.x);
        float g1 = fmaf(s1.w, g2, s1.y);
        float b1 = fmaf(s1.w, b2, s1.z);
        out[3 * i + 0] = fmaf(light, r1, ar);
        out[3 * i + 1] = fmaf(light, g1, ag);
        out[3 * i + 2] = fmaf(light, b1, ab);
    }
}

// ---- fused cooperative kernel: convert -> grid.sync -> render --------------
__global__ __launch_bounds__(256, 4) void volrend_fused(
    const float4* __restrict__ grid,
    unsigned int* __restrict__ gq,
    const float* __restrict__ origins,
    const float* __restrict__ dirs,
    float* __restrict__ out,
    int nblocks)
{
    __shared__ float4 lds[64 * (NSEG - 1)];

    // phase 1: convert (grid-stride over 524288 uint4 slots)
    int gtid = blockIdx.x * blockDim.x + threadIdx.x;
    int nthreads = nblocks * 256;
    uint4* gq4 = (uint4*)gq;
    for (int u = gtid; u < N_VOX / 4; u += nthreads) {
        cvt_one(grid, gq4, u);
    }

    cg::this_grid().sync();

    // phase 2: render (block == 64-ray group)
    render_body(gq, origins, dirs, out, lds, blockIdx.x);
}

// ---- standalone pair (fallback if cooperative launch unavailable) ----------
__global__ __launch_bounds__(256) void cvt_brick(
    const float4* __restrict__ g, uint4* __restrict__ gq4)
{
    int tid = blockIdx.x * blockDim.x + threadIdx.x;
    if (tid >= N_VOX / 4) return;
    cvt_one(g, gq4, tid);
}

__global__ __launch_bounds__(256) void volrend_seg(
    const unsigned int* __restrict__ gq,
    const float* __restrict__ origins,
    const float* __restrict__ dirs,
    float* __restrict__ out,
    int B)
{
    __shared__ float4 lds[64 * (NSEG - 1)];
    render_body(gq, origins, dirs, out, lds, blockIdx.x);
}

// ---- fallback: render straight from fp32 grid (if ws too small) ------------
__global__ __launch_bounds__(256) void volrend_f32(
    const float* __restrict__ grid,
    const float* __restrict__ origins,
    const float* __restrict__ dirs,
    float* __restrict__ out,
    int B)
{
    int i = blockIdx.x * blockDim.x + threadIdx.x;
    if (i >= B) return;

    float ox, oy, oz, dx, dy, dz, ix, iy, iz, tmin, tmax;
    ray_setup(origins, dirs, i, ox, oy, oz, dx, dy, dz, ix, iy, iz, tmin, tmax);

    const float4* __restrict__ g4 = (const float4*)grid;

    float t = tmin;
    float light = 1.0f;
    float ar = 0.0f, ag = 0.0f, ab = 0.0f;

    for (int chunk = 0; chunk < N_STEPS / PIPE; ++chunk) {
        if (t >= tmax) break;

        float4 val[PIPE];
        float del[PIPE];
        float tl = t;

        #pragma unroll
        for (int p = 0; p < PIPE; ++p) {
            int i0, i1, i2; float d;
            geom_step(tl, tmax, ox, oy, oz, dx, dy, dz, ix, iy, iz,
                      i0, i1, i2, d);
            val[p] = g4[(i0 * R_DIM + i1) * R_DIM + i2];
            del[p] = d;
            tl = __fadd_rn(tl, d);
        }

        #pragma unroll
        for (int p = 0; p < PIPE; ++p) {
            float sigma = fmaxf(val[p].w, 0.0f);
            float att = __expf(-del[p] * sigma);
            float w = light * (1.0f - att);
            ar = fmaf(w, sigmoid_fast(val[p].x), ar);
            ag = fmaf(w, sigmoid_fast(val[p].y), ag);
            ab = fmaf(w, sigmoid_fast(val[p].z), ab);
            light *= att;
        }

        t = tl;
    }

    out[3 * i + 0] = ar + light;
    out[3 * i + 1] = ag + light;
    out[3 * i + 2] = ab + light;
}

extern "C" void kernel_launch(void* const* d_in, const int* in_sizes, int n_in,
                              void* d_out, int out_size, void* d_ws, size_t ws_size,
                              hipStream_t stream) {
    const float* grid    = (const float*)d_in[0];
    const float* origins = (const float*)d_in[1];
    const float* dirs    = (const float*)d_in[2];
    float* out = (float*)d_out;

    int B = in_sizes[1] / 3;

    size_t need = (size_t)N_VOX * 4;   // brick-ordered u8x4 voxels, 8.4 MB
    if (ws_size >= need && (B % 64) == 0) {
        unsigned int* gq = (unsigned int*)d_ws;
        int nblocks = B / 64;          // 1024 blocks x 256 thr (co-resident)

        const float4* gridv = (const float4*)grid;
        void* args[] = { (void*)&gridv, (void*)&gq, (void*)&origins,
                         (void*)&dirs, (void*)&out, (void*)&nblocks };
        hipError_t rc = hipLaunchCooperativeKernel(
            (const void*)volrend_fused, dim3(nblocks), dim3(256),
            args, 0, stream);
        if (rc != hipSuccess) {
            // cooperative launch unavailable -> proven 2-kernel path
            cvt_brick<<<(N_VOX / 4 + 255) / 256, 256, 0, stream>>>(
                gridv, (uint4*)gq);
            volrend_seg<<<nblocks, 256, 0, stream>>>(gq, origins, dirs,
                                                     out, B);
        }
    } else {
        volrend_f32<<<(B + 255) / 256, 256, 0, stream>>>(grid, origins, dirs,
                                                         out, B);
    }
}

// Round 15
// 116.368 us; speedup vs baseline: 1.9077x; 1.9077x over previous
//
#include <hip/hip_runtime.h>

// VolumeRenderer R15 = champion config (R12 structure + R13's coalesced cvt).
// R14 post-mortem: cooperative fusion lost 107us -- grid.sync on 8 non-
// coherent XCD L2s forces writeback+invalidate; phase-2 gathers restart cold
// (143us fused vs ~47us separate). Reverted.
// Final model: bench 115 = 45us harness ws-repoison + ~12us launch/restore
// + cvt ~10 (streaming floor 7) + render ~35. Render is Little's-law bound:
// ~123k wave-steps x ~64 distinct lines / (64 MSHR x 256 CU x 2.4GHz) ~ 35us.
// Tested and closed: waves 2x/4x (saturating), footprint (null), masks
// (negative), PIPE (null), fusion (negative).

constexpr int   R_DIM    = 128;
constexpr int   N_VOX    = R_DIM * R_DIM * R_DIM;
constexpr int   N_STEPS  = 192;
constexpr int   NSEG     = 4;
constexpr int   SEG_LEN  = N_STEPS / NSEG;   // 48
constexpr float STEP_SZ  = 0.001f;
constexpr float CUBE_SZ  = 1.0f / 128.0f;
constexpr int   PIPE     = 8;
constexpr float SIG_MAX  = 5.5f;

__device__ __forceinline__ float sigmoid_fast(float x) {
    return __builtin_amdgcn_rcpf(1.0f + __expf(-x));
}

__device__ __forceinline__ int clamp_idx(float v) {
    int i = (int)floorf(v);
    i = i < 0 ? 0 : i;
    i = i > (R_DIM - 1) ? (R_DIM - 1) : i;
    return i;
}

// One geometric DDA step -> cell coords + exact delta. Single definition, all
// IEEE __f*_rn (no contraction): prewalk/render t-sequences bit-identical.
// smin==0 exactly (f in [0,1] -> every per-axis lo <= 0).
__device__ __forceinline__ void geom_step(
    float tl, float tmax,
    float ox, float oy, float oz, float dx, float dy, float dz,
    float ix, float iy, float iz,
    int& i0, int& i1, int& i2, float& d)
{
    float px = __fmul_rn(__fadd_rn(ox, __fmul_rn(tl, dx)), (float)R_DIM);
    float py = __fmul_rn(__fadd_rn(oy, __fmul_rn(tl, dy)), (float)R_DIM);
    float pz = __fmul_rn(__fadd_rn(oz, __fmul_rn(tl, dz)), (float)R_DIM);
    i0 = clamp_idx(px);
    i1 = clamp_idx(py);
    i2 = clamp_idx(pz);

    float fx = __fsub_rn(px, (float)i0);
    float fy = __fsub_rn(py, (float)i1);
    float fz = __fsub_rn(pz, (float)i2);

    float t1x = __fmul_rn(-fx, ix), t2x = __fadd_rn(t1x, ix);
    float t1y = __fmul_rn(-fy, iy), t2y = __fadd_rn(t1y, iy);
    float t1z = __fmul_rn(-fz, iz), t2z = __fadd_rn(t1z, iz);
    float hix = fmaxf(t1x, t2x);
    float hiy = fmaxf(t1y, t2y);
    float hiz = fmaxf(t1z, t2z);
    float smax = fminf(fminf(fminf(hix, hiy), hiz), 1e9f);

    d = __fadd_rn(__fmul_rn(smax, CUBE_SZ), STEP_SZ);
    d = (tl < tmax) ? d : 0.0f;   // inactive -> exact no-op (t frozen)
}

__device__ __forceinline__ void ray_setup(
    const float* __restrict__ origins, const float* __restrict__ dirs, int i,
    float& ox, float& oy, float& oz, float& dx, float& dy, float& dz,
    float& ix, float& iy, float& iz, float& tmin, float& tmax)
{
    ox = origins[3 * i + 0];
    oy = origins[3 * i + 1];
    oz = origins[3 * i + 2];
    dx = dirs[3 * i + 0];
    dy = dirs[3 * i + 1];
    dz = dirs[3 * i + 2];

    float n2 = __fadd_rn(__fadd_rn(__fmul_rn(dx, dx), __fmul_rn(dy, dy)),
                         __fmul_rn(dz, dz));
    float nrm = sqrtf(n2);
    dx = dx / nrm;
    dy = dy / nrm;
    dz = dz / nrm;

    ix = 1.0f / __fadd_rn(dx, 1e-9f);
    iy = 1.0f / __fadd_rn(dy, 1e-9f);
    iz = 1.0f / __fadd_rn(dz, 1e-9f);

    float t1x = __fmul_rn(-ox, ix), t2x = __fadd_rn(t1x, ix);
    float t1y = __fmul_rn(-oy, iy), t2y = __fadd_rn(t1y, iy);
    float t1z = __fmul_rn(-oz, iz), t2z = __fadd_rn(t1z, iz);
    float lox = fminf(t1x, t2x), hix = fmaxf(t1x, t2x);
    float loy = fminf(t1y, t2y), hiy = fmaxf(t1y, t2y);
    float loz = fminf(t1z, t2z), hiz = fmaxf(t1z, t2z);
    tmin = fmaxf(fmaxf(fmaxf(lox, loy), loz), 0.0f);
    tmax = fminf(fminf(fminf(hix, hiy), hiz), 1e9f);
}

// ---- pre-pass: fp32 grid -> brick-ordered u8x4 voxels ----------------------
// 16 threads per brick; thread j handles voxels loc = 4j..4j+3 (lz 0..3):
// 64B read run per thread, uint4 write at dst = bid*16 + j -> consecutive
// threads write consecutive uint4 (fully coalesced).
__device__ __forceinline__ unsigned pack_voxel(float4 v) {
    unsigned ur = (unsigned)__float2int_rn(sigmoid_fast(v.x) * 255.0f);
    unsigned ug = (unsigned)__float2int_rn(sigmoid_fast(v.y) * 255.0f);
    unsigned ub = (unsigned)__float2int_rn(sigmoid_fast(v.z) * 255.0f);
    unsigned us = (unsigned)__float2int_rn(
        fminf(fmaxf(v.w, 0.0f), SIG_MAX) * (255.0f / SIG_MAX));
    return ur | (ug << 8) | (ub << 16) | (us << 24);
}

__global__ __launch_bounds__(256) void cvt_brick(
    const float4* __restrict__ g, uint4* __restrict__ gq4)
{
    int tid = blockIdx.x * blockDim.x + threadIdx.x;
    if (tid >= N_VOX / 4) return;
    int bid = tid >> 4;             // brick id = bx<<10 | by<<5 | bz
    int j   = tid & 15;             // lx<<2 | ly
    int bx = bid >> 10, by = (bid >> 5) & 31, bz = bid & 31;
    int lx = j >> 2, ly = j & 3;

    int x = (bx << 2) | lx;
    int y = (by << 2) | ly;
    int src = (x * R_DIM + y) * R_DIM + (bz << 2);   // float4 index, lz=0

    float4 v0 = g[src + 0];
    float4 v1 = g[src + 1];
    float4 v2 = g[src + 2];
    float4 v3 = g[src + 3];

    uint4 o;
    o.x = pack_voxel(v0);
    o.y = pack_voxel(v1);
    o.z = pack_voxel(v2);
    o.w = pack_voxel(v3);

    gq4[bid * 16 + j] = o;          // coalesced
}

// ---- render: 4 waves/block; wave s renders steps [s*48, s*48+48) -----------
__global__ __launch_bounds__(256) void volrend_seg(
    const unsigned int* __restrict__ gq,   // brick-ordered u8x4, 8.4 MB
    const float* __restrict__ origins,
    const float* __restrict__ dirs,
    float* __restrict__ out,
    int B)
{
    __shared__ float4 lds[64 * (NSEG - 1)];

    int lane = threadIdx.x & 63;
    int seg  = threadIdx.x >> 6;
    int i = blockIdx.x * 64 + lane;

    float ox, oy, oz, dx, dy, dz, ix, iy, iz, tmin, tmax;
    ray_setup(origins, dirs, i, ox, oy, oz, dx, dy, dz, ix, iy, iz, tmin, tmax);

    float t = tmin;

    // --- prewalk: seg*48 geometry-only steps (bit-exact, no loads) ---------
    int pre_chunks = seg * (SEG_LEN / PIPE);
    for (int c = 0; c < pre_chunks; ++c) {
        if (t >= tmax) break;
        #pragma unroll
        for (int p = 0; p < PIPE; ++p) {
            int i0, i1, i2; float d;
            geom_step(t, tmax, ox, oy, oz, dx, dy, dz, ix, iy, iz,
                      i0, i1, i2, d);
            t = __fadd_rn(t, d);
        }
    }

    // --- render 48 steps with local transmittance --------------------------
    float light = 1.0f;
    float ar = 0.0f, ag = 0.0f, ab = 0.0f;

    for (int chunk = 0; chunk < SEG_LEN / PIPE; ++chunk) {
        if (t >= tmax) break;

        unsigned int val[PIPE];
        float del[PIPE];
        float tl = t;

        #pragma unroll
        for (int p = 0; p < PIPE; ++p) {
            int i0, i1, i2; float d;
            geom_step(tl, tmax, ox, oy, oz, dx, dy, dz, ix, iy, iz,
                      i0, i1, i2, d);
            unsigned bid = ((unsigned)(i0 >> 2) << 10) |
                           ((unsigned)(i1 >> 2) << 5) |
                           (unsigned)(i2 >> 2);
            unsigned loc = ((unsigned)(i0 & 3) << 4) |
                           ((unsigned)(i1 & 3) << 2) |
                           (unsigned)(i2 & 3);
            val[p] = gq[(bid << 6) | loc];   // dead voxel: sigma-u8==0 -> att=1
            del[p] = d;
            tl = __fadd_rn(tl, d);
        }

        #pragma unroll
        for (int p = 0; p < PIPE; ++p) {
            unsigned int v = val[p];
            // byte-extract casts compile to v_cvt_f32_ubyte0..3
            float r  = (float)(v & 255u)         * (1.0f / 255.0f);
            float gg = (float)((v >> 8) & 255u)  * (1.0f / 255.0f);
            float b  = (float)((v >> 16) & 255u) * (1.0f / 255.0f);
            float sg = (float)(v >> 24)          * (SIG_MAX / 255.0f);
            float att = __expf(-del[p] * sg);
            float w = light * (1.0f - att);
            ar = fmaf(w, r, ar);
            ag = fmaf(w, gg, ag);
            ab = fmaf(w, b, ab);
            light *= att;
        }

        t = tl;
    }

    // --- compose: out = A0 + L0*(A1 + L1*(A2 + L2*(A3 + L3))) --------------
    if (seg > 0) {
        lds[(seg - 1) * 64 + lane] = make_float4(ar, ag, ab, light);
    }
    __syncthreads();
    if (seg == 0) {
        float4 s1 = lds[0 * 64 + lane];
        float4 s2 = lds[1 * 64 + lane];
        float4 s3 = lds[2 * 64 + lane];
        float r3 = s3.x + s3.w, g3 = s3.y + s3.w, b3 = s3.z + s3.w;
        float r2 = fmaf(s2.w, r3, s2.x);
        float g2 = fmaf(s2.w, g3, s2.y);
        float b2 = fmaf(s2.w, b3, s2.z);
        float r1 = fmaf(s1.w, r2, s1.x);
        float g1 = fmaf(s1.w, g2, s1.y);
        float b1 = fmaf(s1.w, b2, s1.z);
        out[3 * i + 0] = fmaf(light, r1, ar);
        out[3 * i + 1] = fmaf(light, g1, ag);
        out[3 * i + 2] = fmaf(light, b1, ab);
    }
}

// ---- fallback: render straight from fp32 grid (if ws too small) ------------
__global__ __launch_bounds__(256) void volrend_f32(
    const float* __restrict__ grid,
    const float* __restrict__ origins,
    const float* __restrict__ dirs,
    float* __restrict__ out,
    int B)
{
    int i = blockIdx.x * blockDim.x + threadIdx.x;
    if (i >= B) return;

    float ox, oy, oz, dx, dy, dz, ix, iy, iz, tmin, tmax;
    ray_setup(origins, dirs, i, ox, oy, oz, dx, dy, dz, ix, iy, iz, tmin, tmax);

    const float4* __restrict__ g4 = (const float4*)grid;

    float t = tmin;
    float light = 1.0f;
    float ar = 0.0f, ag = 0.0f, ab = 0.0f;

    for (int chunk = 0; chunk < N_STEPS / PIPE; ++chunk) {
        if (t >= tmax) break;

        float4 val[PIPE];
        float del[PIPE];
        float tl = t;

        #pragma unroll
        for (int p = 0; p < PIPE; ++p) {
            int i0, i1, i2; float d;
            geom_step(tl, tmax, ox, oy, oz, dx, dy, dz, ix, iy, iz,
                      i0, i1, i2, d);
            val[p] = g4[(i0 * R_DIM + i1) * R_DIM + i2];
            del[p] = d;
            tl = __fadd_rn(tl, d);
        }

        #pragma unroll
        for (int p = 0; p < PIPE; ++p) {
            float sigma = fmaxf(val[p].w, 0.0f);
            float att = __expf(-del[p] * sigma);
            float w = light * (1.0f - att);
            ar = fmaf(w, sigmoid_fast(val[p].x), ar);
            ag = fmaf(w, sigmoid_fast(val[p].y), ag);
            ab = fmaf(w, sigmoid_fast(val[p].z), ab);
            light *= att;
        }

        t = tl;
    }

    out[3 * i + 0] = ar + light;
    out[3 * i + 1] = ag + light;
    out[3 * i + 2] = ab + light;
}

extern "C" void kernel_launch(void* const* d_in, const int* in_sizes, int n_in,
                              void* d_out, int out_size, void* d_ws, size_t ws_size,
                              hipStream_t stream) {
    const float* grid    = (const float*)d_in[0];
    const float* origins = (const float*)d_in[1];
    const float* dirs    = (const float*)d_in[2];
    float* out = (float*)d_out;

    int B = in_sizes[1] / 3;

    size_t need = (size_t)N_VOX * 4;   // brick-ordered u8x4 voxels, 8.4 MB
    if (ws_size >= need && (B % 64) == 0) {
        uint4* gq4 = (uint4*)d_ws;
        cvt_brick<<<(N_VOX / 4 + 255) / 256, 256, 0, stream>>>(
            (const float4*)grid, gq4);
        volrend_seg<<<B / 64, 256, 0, stream>>>(
            (const unsigned int*)gq4, origins, dirs, out, B);
    } else {
        volrend_f32<<<(B + 255) / 256, 256, 0, stream>>>(grid, origins, dirs,
                                                         out, B);
    }
}